// Round 1
// baseline (1167.228 us; speedup 1.0000x reference)
//
#include <hip/hip_runtime.h>
#include <math.h>

typedef __attribute__((ext_vector_type(8))) short short8;
typedef __attribute__((ext_vector_type(8))) unsigned short ushort8;
typedef __attribute__((ext_vector_type(4))) float f32x4;

__device__ __forceinline__ float b2f(unsigned short h) {
    union { unsigned int u; float f; } c; c.u = ((unsigned int)h) << 16; return c.f;
}
__device__ __forceinline__ unsigned short f2b(float x) {
    union { float f; unsigned int u; } c; c.f = x;
    unsigned int r = c.u + 0x7fffu + ((c.u >> 16) & 1u);
    return (unsigned short)(r >> 16);
}

// ---------------- cast f32 -> bf16 (vectorized) ----------------
__global__ __launch_bounds__(256) void cast_f2b(const float* __restrict__ in,
                                                unsigned short* __restrict__ out, int n4) {
    int i = blockIdx.x * 256 + threadIdx.x;
    if (i >= n4) return;
    float4 f = ((const float4*)in)[i];
    ushort4 o; o.x = f2b(f.x); o.y = f2b(f.y); o.z = f2b(f.z); o.w = f2b(f.w);
    ((ushort4*)out)[i] = o;
}

// ---------------- wave-per-row LayerNorm ----------------
template <int DD, bool INB, bool OUTB>
__global__ __launch_bounds__(256) void ln_rows(const void* __restrict__ in_, void* __restrict__ out_,
                                               const float* __restrict__ g, const float* __restrict__ bb,
                                               int nrows) {
    const int wv = threadIdx.x >> 6, l = threadIdx.x & 63;
    const int row = blockIdx.x * 4 + wv;
    if (row >= nrows) return;
    constexpr int NC = DD / 256;  // float4/ushort4 chunks per lane
    float v[DD / 64];
    if constexpr (INB) {
        const ushort4* in = (const ushort4*)((const unsigned short*)in_ + (size_t)row * DD);
#pragma unroll
        for (int c = 0; c < NC; ++c) {
            ushort4 u = in[l + 64 * c];
            v[4*c] = b2f(u.x); v[4*c+1] = b2f(u.y); v[4*c+2] = b2f(u.z); v[4*c+3] = b2f(u.w);
        }
    } else {
        const float4* in = (const float4*)((const float*)in_ + (size_t)row * DD);
#pragma unroll
        for (int c = 0; c < NC; ++c) {
            float4 u = in[l + 64 * c];
            v[4*c] = u.x; v[4*c+1] = u.y; v[4*c+2] = u.z; v[4*c+3] = u.w;
        }
    }
    float s = 0.f, s2 = 0.f;
#pragma unroll
    for (int i = 0; i < DD / 64; ++i) { s += v[i]; s2 += v[i] * v[i]; }
#pragma unroll
    for (int o = 32; o > 0; o >>= 1) { s += __shfl_xor(s, o, 64); s2 += __shfl_xor(s2, o, 64); }
    const float mu = s * (1.0f / DD);
    const float var = s2 * (1.0f / DD) - mu * mu;
    const float rs = rsqrtf(var + 1e-5f);
    if constexpr (OUTB) {
        ushort4* out = (ushort4*)((unsigned short*)out_ + (size_t)row * DD);
#pragma unroll
        for (int c = 0; c < NC; ++c) {
            int e = (l + 64 * c) * 4;
            ushort4 o4;
            o4.x = f2b((v[4*c]   - mu) * rs * g[e]   + bb[e]);
            o4.y = f2b((v[4*c+1] - mu) * rs * g[e+1] + bb[e+1]);
            o4.z = f2b((v[4*c+2] - mu) * rs * g[e+2] + bb[e+2]);
            o4.w = f2b((v[4*c+3] - mu) * rs * g[e+3] + bb[e+3]);
            out[l + 64 * c] = o4;
        }
    } else {
        float4* out = (float4*)((float*)out_ + (size_t)row * DD);
#pragma unroll
        for (int c = 0; c < NC; ++c) {
            int e = (l + 64 * c) * 4;
            float4 o4;
            o4.x = (v[4*c]   - mu) * rs * g[e]   + bb[e];
            o4.y = (v[4*c+1] - mu) * rs * g[e+1] + bb[e+1];
            o4.z = (v[4*c+2] - mu) * rs * g[e+2] + bb[e+2];
            o4.w = (v[4*c+3] - mu) * rs * g[e+3] + bb[e+3];
            out[l + 64 * c] = o4;
        }
    }
}

// ---------------- qp = LN(queries) @ wq^T + bq (tiny, batch-independent) ----------------
__global__ __launch_bounds__(256) void qp_kernel(const float* __restrict__ qn, const float* __restrict__ wq,
                                                 const float* __restrict__ bq, float* __restrict__ qp) {
    int q = blockIdx.x / 3;
    int col = (blockIdx.x % 3) * 256 + threadIdx.x;
    const float4* a = (const float4*)(qn + q * 768);
    const float4* wr = (const float4*)(wq + (size_t)col * 768);
    float s = 0.f;
#pragma unroll 8
    for (int k = 0; k < 192; ++k) {
        float4 xx = a[k], yy = wr[k];
        s += xx.x * yy.x + xx.y * yy.y + xx.z * yy.z + xx.w * yy.w;
    }
    qp[q * 768 + col] = s + bq[col];
}

// ---------------- MFMA GEMM: C[M,N] = A[M,K](bf16) * W[N,K](bf16)^T + bias, epilogue variants ----
// 128x128 tile, BK=64, 256 threads (4 waves, each 64x64), global_load_lds staging with
// XOR-8 chunk swizzle (row-stride 128B would otherwise be a heavy bank conflict on ds_read_b128).
__device__ __forceinline__ void gll16(const void* g, void* l) {
    __builtin_amdgcn_global_load_lds((const __attribute__((address_space(1))) unsigned int*)g,
                                     (__attribute__((address_space(3))) unsigned int*)l, 16, 0, 0);
}

__device__ __forceinline__ void stage_tile(const unsigned short* gbase, int ldg,
                                           unsigned short* lds, int tid) {
    int wuni = tid & ~63;
#pragma unroll
    for (int it = 0; it < 4; ++it) {
        int s = it * 256 + tid;
        int r = s >> 3, c = s & 7;
        int cc = c ^ (r & 7);  // inverse swizzle on the global source; LDS stays linear
        gll16(gbase + (size_t)r * ldg + cc * 8, lds + (size_t)(it * 256 + wuni) * 8);
    }
}

// EPI: 0 bias->bf16 | 1 bias+queries[row&7]->f32 | 2 bias+gelu->bf16 | 3 bias+aux[row]->bf16 | 4 bias->f32
template <int EPI>
__global__ __launch_bounds__(256) void gemm_bf16(
    const unsigned short* __restrict__ A, const unsigned short* __restrict__ W,
    const float* __restrict__ bias, void* __restrict__ out,
    const float* __restrict__ aux, int K, int N) {
    __shared__ __align__(16) unsigned short lA[128 * 64];
    __shared__ __align__(16) unsigned short lB[128 * 64];
    const int tid = threadIdx.x;
    const int l = tid & 63, w = tid >> 6;
    const int bm0 = blockIdx.y * 128, bn0 = blockIdx.x * 128;
    const int wm = (w >> 1) * 64, wn = (w & 1) * 64;
    const int l15 = l & 15, lk = l >> 4;
    f32x4 acc[4][4] = {};
    const int nk = K >> 6;
    const unsigned short* Abase = A + (size_t)bm0 * K;
    const unsigned short* Wbase = W + (size_t)bn0 * K;
    for (int kt = 0; kt < nk; ++kt) {
        stage_tile(Abase + kt * 64, K, lA, tid);
        stage_tile(Wbase + kt * 64, K, lB, tid);
        __syncthreads();  // compiler drains vmcnt before s_barrier
        short8 af[4], bf[4];
#pragma unroll
        for (int kk = 0; kk < 2; ++kk) {
#pragma unroll
            for (int mf = 0; mf < 4; ++mf) {
                int r = wm + mf * 16 + l15;
                int c = (kk * 4 + lk) ^ (r & 7);
                af[mf] = *(const short8*)(lA + r * 64 + c * 8);
            }
#pragma unroll
            for (int nf = 0; nf < 4; ++nf) {
                int r = wn + nf * 16 + l15;
                int c = (kk * 4 + lk) ^ (r & 7);
                bf[nf] = *(const short8*)(lB + r * 64 + c * 8);
            }
#pragma unroll
            for (int mf = 0; mf < 4; ++mf)
#pragma unroll
                for (int nf = 0; nf < 4; ++nf)
                    acc[mf][nf] = __builtin_amdgcn_mfma_f32_16x16x32_bf16(af[mf], bf[nf], acc[mf][nf], 0, 0, 0);
        }
        __syncthreads();
    }
    // epilogue: D row = (lane>>4)*4 + reg, col = lane&15  [m89-verified mapping]
    const int row0 = bm0 + wm + (lk << 2);
    const int col0 = bn0 + wn + l15;
#pragma unroll
    for (int nf = 0; nf < 4; ++nf) {
        int col = col0 + nf * 16;
        float bv = bias[col];
#pragma unroll
        for (int mf = 0; mf < 4; ++mf) {
#pragma unroll
            for (int r = 0; r < 4; ++r) {
                int row = row0 + mf * 16 + r;
                float v = acc[mf][nf][r] + bv;
                size_t idx = (size_t)row * N + col;
                if constexpr (EPI == 0) {
                    ((unsigned short*)out)[idx] = f2b(v);
                } else if constexpr (EPI == 1) {
                    v += aux[(row & 7) * N + col];
                    ((float*)out)[idx] = v;
                } else if constexpr (EPI == 2) {
                    v = 0.5f * v * (1.0f + erff(v * 0.70710678118f));
                    ((unsigned short*)out)[idx] = f2b(v);
                } else if constexpr (EPI == 3) {
                    v += aux[idx];
                    ((unsigned short*)out)[idx] = f2b(v);
                } else {
                    ((float*)out)[idx] = v;
                }
            }
        }
    }
}

// ---------------- attention: one block per (b,h); 49 keys, NQ=8, DH=96 ----------------
__global__ __launch_bounds__(64) void attn_kernel(const unsigned short* __restrict__ kvp,
                                                  const float* __restrict__ qp,
                                                  unsigned short* __restrict__ ctx) {
    __shared__ __align__(16) unsigned short kt[49 * 96];
    __shared__ __align__(16) unsigned short vt[49 * 96];
    __shared__ float qs[8 * 96];
    __shared__ float sc[8 * 49];
    const int b = blockIdx.x >> 3, h = blockIdx.x & 7;
    const int t = threadIdx.x;
    const unsigned short* base = kvp + (size_t)b * 49 * 1536 + h * 96;
    for (int ch = t; ch < 588; ch += 64) {  // 49 rows * 12 chunks of 8 bf16
        int n = ch / 12, cb = ch - n * 12;
        const unsigned short* src = base + (size_t)n * 1536 + cb * 8;
        *(ushort8*)(kt + ch * 8) = *(const ushort8*)src;
        *(ushort8*)(vt + ch * 8) = *(const ushort8*)(src + 768);
    }
    for (int i = t; i < 768; i += 64) {
        int q = i / 96, d = i - q * 96;
        qs[i] = qp[q * 768 + h * 96 + d];
    }
    __syncthreads();
    const int q = t >> 3;
    const int n0 = t & 7;
    for (int j = 0; j < 7; ++j) {
        int n = n0 + 8 * j;
        if (n < 49) {
            const float4* qv = (const float4*)(qs + q * 96);
            const ushort4* kv4 = (const ushort4*)(kt + n * 96);
            float s = 0.f;
#pragma unroll
            for (int dc = 0; dc < 24; ++dc) {
                float4 qf = qv[dc]; ushort4 kf = kv4[dc];
                s += qf.x * b2f(kf.x) + qf.y * b2f(kf.y) + qf.z * b2f(kf.z) + qf.w * b2f(kf.w);
            }
            sc[q * 49 + n] = s * 0.10206207262f;  // 1/sqrt(96)
        }
    }
    __syncthreads();
    if (t < 8) {
        float m = -1e30f;
        for (int n = 0; n < 49; ++n) m = fmaxf(m, sc[t * 49 + n]);
        float sum = 0.f;
        for (int n = 0; n < 49; ++n) { float e = __expf(sc[t * 49 + n] - m); sc[t * 49 + n] = e; sum += e; }
        float inv = 1.0f / sum;
        for (int n = 0; n < 49; ++n) sc[t * 49 + n] *= inv;
    }
    __syncthreads();
    unsigned short* orow = ctx + (size_t)(b * 8 + q) * 768 + h * 96;
#pragma unroll
    for (int j = 0; j < 3; ++j) {
        int dbase = ((t & 7) + 8 * j) * 4;
        float a0 = 0, a1 = 0, a2 = 0, a3 = 0;
        for (int n = 0; n < 49; ++n) {
            float a = sc[q * 49 + n];
            ushort4 vv = *(const ushort4*)(vt + n * 96 + dbase);
            a0 += a * b2f(vv.x); a1 += a * b2f(vv.y); a2 += a * b2f(vv.z); a3 += a * b2f(vv.w);
        }
        ushort4 o; o.x = f2b(a0); o.y = f2b(a1); o.z = f2b(a2); o.w = f2b(a3);
        *(ushort4*)(orow + dbase) = o;
    }
}

// ---------------- host ----------------
extern "C" void kernel_launch(void* const* d_in, const int* in_sizes, int n_in,
                              void* d_out, int out_size, void* d_ws, size_t ws_size,
                              hipStream_t stream) {
    (void)in_sizes; (void)n_in; (void)out_size;
    const float* features      = (const float*)d_in[0];
    const float* input_proj_w  = (const float*)d_in[1];
    const float* input_proj_b  = (const float*)d_in[2];
    const float* queries       = (const float*)d_in[3];
    const float* ln_q_g        = (const float*)d_in[4];
    const float* ln_q_b        = (const float*)d_in[5];
    const float* ln_kv_g       = (const float*)d_in[6];
    const float* ln_kv_b       = (const float*)d_in[7];
    const float* in_proj_w     = (const float*)d_in[8];
    const float* in_proj_b     = (const float*)d_in[9];
    const float* out_proj_w    = (const float*)d_in[10];
    const float* out_proj_b    = (const float*)d_in[11];
    const float* ln_ff_g       = (const float*)d_in[12];
    const float* ln_ff_b       = (const float*)d_in[13];
    const float* ffn_w1        = (const float*)d_in[14];
    const float* ffn_b1        = (const float*)d_in[15];
    const float* ffn_w2        = (const float*)d_in[16];
    const float* ffn_b2        = (const float*)d_in[17];
    const float* output_proj_w = (const float*)d_in[18];
    const float* output_proj_b = (const float*)d_in[19];
    const float* final_g       = (const float*)d_in[20];
    const float* final_b       = (const float*)d_in[21];

    char* ws = (char*)d_ws;
    size_t off = 0;
    auto alloc = [&](size_t bytes) -> char* {
        char* r = ws + off; off += (bytes + 255) & ~(size_t)255; return r;
    };
    unsigned short* featb = (unsigned short*)alloc(100352ull * 320 * 2);   // 64.2 MB
    unsigned short* kvbuf = (unsigned short*)alloc(100352ull * 768 * 2);   // 154 MB
    unsigned short* kvp   = (unsigned short*)alloc(100352ull * 1536 * 2);  // 308 MB
    unsigned short* winb  = (unsigned short*)alloc(768ull * 320 * 2);
    unsigned short* wkvb  = (unsigned short*)alloc(1536ull * 768 * 2);
    unsigned short* woutb = (unsigned short*)alloc(768ull * 768 * 2);
    unsigned short* w1b   = (unsigned short*)alloc(768ull * 768 * 2);
    unsigned short* w2b   = (unsigned short*)alloc(768ull * 768 * 2);
    unsigned short* wopb  = (unsigned short*)alloc(3072ull * 768 * 2);
    float* qnorm          = (float*)alloc(8 * 768 * 4);
    float* qp             = (float*)alloc(8 * 768 * 4);
    if (off > ws_size) return;  // workspace too small: fail visibly (output stays poisoned)

    // region reuse (all dead by the time they're overwritten):
    unsigned short* ctx = featb;                                    // 25 MB <= 64 MB
    float* x            = (float*)kvbuf;                            // 50 MB
    unsigned short* hn  = (unsigned short*)((char*)kvbuf + 50331648);
    unsigned short* f1  = (unsigned short*)((char*)kvbuf + 75497472);
    unsigned short* x2  = (unsigned short*)((char*)kvbuf + 100663296);

    // weight/input casts to bf16
    cast_f2b<<<31360, 256, 0, stream>>>(features, featb, 8028160);
    cast_f2b<<<240,   256, 0, stream>>>(input_proj_w, winb, 61440);
    cast_f2b<<<1152,  256, 0, stream>>>(in_proj_w + 768 * 768, wkvb, 294912);  // [wk; wv]
    cast_f2b<<<576,   256, 0, stream>>>(out_proj_w, woutb, 147456);
    cast_f2b<<<576,   256, 0, stream>>>(ffn_w1, w1b, 147456);
    cast_f2b<<<576,   256, 0, stream>>>(ffn_w2, w2b, 147456);
    cast_f2b<<<2304,  256, 0, stream>>>(output_proj_w, wopb, 589824);

    // batch-independent query path (fp32, tiny)
    ln_rows<768, false, false><<<2, 256, 0, stream>>>(queries, qnorm, ln_q_g, ln_q_b, 8);
    qp_kernel<<<24, 256, 0, stream>>>(qnorm, in_proj_w, in_proj_b, qp);

    // kv = features @ Win^T + b  -> bf16
    gemm_bf16<0><<<dim3(6, 784), 256, 0, stream>>>(featb, winb, input_proj_b, kvbuf, nullptr, 320, 768);
    // LN(kv) in place
    ln_rows<768, true, true><<<25088, 256, 0, stream>>>(kvbuf, kvbuf, ln_kv_g, ln_kv_b, 100352);
    // [k; v] = kv_norm @ [wk; wv]^T + b  -> bf16 (100352 x 1536)
    gemm_bf16<0><<<dim3(12, 784), 256, 0, stream>>>(kvbuf, wkvb, in_proj_b + 768, kvp, nullptr, 768, 1536);
    // attention per (b, h)
    attn_kernel<<<16384, 64, 0, stream>>>(kvp, qp, ctx);
    // x = ctx @ out_proj^T + b + queries  -> f32
    gemm_bf16<1><<<dim3(6, 128), 256, 0, stream>>>(ctx, woutb, out_proj_b, x, queries, 768, 768);
    // h = LN(x) -> bf16
    ln_rows<768, false, true><<<4096, 256, 0, stream>>>(x, hn, ln_ff_g, ln_ff_b, 16384);
    // f1 = gelu(h @ w1^T + b1) -> bf16
    gemm_bf16<2><<<dim3(6, 128), 256, 0, stream>>>(hn, w1b, ffn_b1, f1, nullptr, 768, 768);
    // x2 = f1 @ w2^T + b2 + x -> bf16
    gemm_bf16<3><<<dim3(6, 128), 256, 0, stream>>>(f1, w2b, ffn_b2, x2, x, 768, 768);
    // out_pre = x2 @ Wop^T + b -> f32 (into d_out)
    gemm_bf16<4><<<dim3(24, 128), 256, 0, stream>>>(x2, wopb, output_proj_b, d_out, nullptr, 768, 3072);
    // final LN in place on d_out
    ln_rows<3072, false, false><<<4096, 256, 0, stream>>>((float*)d_out, (float*)d_out, final_g, final_b, 16384);
}

// Round 2
// 942.923 us; speedup vs baseline: 1.2379x; 1.2379x over previous
//
#include <hip/hip_runtime.h>
#include <math.h>

typedef __attribute__((ext_vector_type(8))) short short8;
typedef __attribute__((ext_vector_type(8))) unsigned short ushort8;
typedef __attribute__((ext_vector_type(4))) float f32x4;

__device__ __forceinline__ float b2f(unsigned short h) {
    union { unsigned int u; float f; } c; c.u = ((unsigned int)h) << 16; return c.f;
}
__device__ __forceinline__ unsigned short f2b(float x) {
    union { float f; unsigned int u; } c; c.f = x;
    unsigned int r = c.u + 0x7fffu + ((c.u >> 16) & 1u);
    return (unsigned short)(r >> 16);
}

// ---------------- cast f32 -> bf16 (vectorized) ----------------
__global__ __launch_bounds__(256) void cast_f2b(const float* __restrict__ in,
                                                unsigned short* __restrict__ out, int n4) {
    int i = blockIdx.x * 256 + threadIdx.x;
    if (i >= n4) return;
    float4 f = ((const float4*)in)[i];
    ushort4 o; o.x = f2b(f.x); o.y = f2b(f.y); o.z = f2b(f.z); o.w = f2b(f.w);
    ((ushort4*)out)[i] = o;
}

// ---------------- wave-per-row LayerNorm ----------------
template <int DD, bool INB, bool OUTB>
__global__ __launch_bounds__(256) void ln_rows(const void* __restrict__ in_, void* __restrict__ out_,
                                               const float* __restrict__ g, const float* __restrict__ bb,
                                               int nrows) {
    const int wv = threadIdx.x >> 6, l = threadIdx.x & 63;
    const int row = blockIdx.x * 4 + wv;
    if (row >= nrows) return;
    constexpr int NC = DD / 256;
    float v[DD / 64];
    if constexpr (INB) {
        const ushort4* in = (const ushort4*)((const unsigned short*)in_ + (size_t)row * DD);
#pragma unroll
        for (int c = 0; c < NC; ++c) {
            ushort4 u = in[l + 64 * c];
            v[4*c] = b2f(u.x); v[4*c+1] = b2f(u.y); v[4*c+2] = b2f(u.z); v[4*c+3] = b2f(u.w);
        }
    } else {
        const float4* in = (const float4*)((const float*)in_ + (size_t)row * DD);
#pragma unroll
        for (int c = 0; c < NC; ++c) {
            float4 u = in[l + 64 * c];
            v[4*c] = u.x; v[4*c+1] = u.y; v[4*c+2] = u.z; v[4*c+3] = u.w;
        }
    }
    float s = 0.f, s2 = 0.f;
#pragma unroll
    for (int i = 0; i < DD / 64; ++i) { s += v[i]; s2 += v[i] * v[i]; }
#pragma unroll
    for (int o = 32; o > 0; o >>= 1) { s += __shfl_xor(s, o, 64); s2 += __shfl_xor(s2, o, 64); }
    const float mu = s * (1.0f / DD);
    const float var = s2 * (1.0f / DD) - mu * mu;
    const float rs = rsqrtf(var + 1e-5f);
    if constexpr (OUTB) {
        ushort4* out = (ushort4*)((unsigned short*)out_ + (size_t)row * DD);
#pragma unroll
        for (int c = 0; c < NC; ++c) {
            int e = (l + 64 * c) * 4;
            ushort4 o4;
            o4.x = f2b((v[4*c]   - mu) * rs * g[e]   + bb[e]);
            o4.y = f2b((v[4*c+1] - mu) * rs * g[e+1] + bb[e+1]);
            o4.z = f2b((v[4*c+2] - mu) * rs * g[e+2] + bb[e+2]);
            o4.w = f2b((v[4*c+3] - mu) * rs * g[e+3] + bb[e+3]);
            out[l + 64 * c] = o4;
        }
    } else {
        float4* out = (float4*)((float*)out_ + (size_t)row * DD);
#pragma unroll
        for (int c = 0; c < NC; ++c) {
            int e = (l + 64 * c) * 4;
            float4 o4;
            o4.x = (v[4*c]   - mu) * rs * g[e]   + bb[e];
            o4.y = (v[4*c+1] - mu) * rs * g[e+1] + bb[e+1];
            o4.z = (v[4*c+2] - mu) * rs * g[e+2] + bb[e+2];
            o4.w = (v[4*c+3] - mu) * rs * g[e+3] + bb[e+3];
            out[l + 64 * c] = o4;
        }
    }
}

// ---------------- qp = LN(queries) @ wq^T + bq (tiny, batch-independent) ----------------
__global__ __launch_bounds__(256) void qp_kernel(const float* __restrict__ qn, const float* __restrict__ wq,
                                                 const float* __restrict__ bq, float* __restrict__ qp) {
    int q = blockIdx.x / 3;
    int col = (blockIdx.x % 3) * 256 + threadIdx.x;
    const float4* a = (const float4*)(qn + q * 768);
    const float4* wr = (const float4*)(wq + (size_t)col * 768);
    float s = 0.f;
#pragma unroll 8
    for (int k = 0; k < 192; ++k) {
        float4 xx = a[k], yy = wr[k];
        s += xx.x * yy.x + xx.y * yy.y + xx.z * yy.z + xx.w * yy.w;
    }
    qp[q * 768 + col] = s + bq[col];
}

// ---------------- qk[hq][e] = scale * sum_d qp[q][h*96+d] * wk[h*96+d][e] ----------------
// bk drops out (constant over n -> cancels in softmax). scale = 1/sqrt(96) folded in.
__global__ __launch_bounds__(256) void qk_build(const float* __restrict__ qp, const float* __restrict__ wk,
                                                unsigned short* __restrict__ qk) {
    const int hq = blockIdx.x, h = hq >> 3, q = hq & 7;
    const float* qv = qp + q * 768 + h * 96;
#pragma unroll
    for (int c = 0; c < 3; ++c) {
        int e = threadIdx.x + 256 * c;
        float s = 0.f;
        for (int d = 0; d < 96; ++d) s += qv[d] * wk[(size_t)(h * 96 + d) * 768 + e];
        qk[hq * 768 + e] = f2b(s * 0.10206207262f);
    }
}

// ---------------- MFMA GEMM machinery ----------------
__device__ __forceinline__ void gll16(const void* g, void* l) {
    __builtin_amdgcn_global_load_lds((const __attribute__((address_space(1))) unsigned int*)g,
                                     (__attribute__((address_space(3))) unsigned int*)l, 16, 0, 0);
}

template <int ROWS>
__device__ __forceinline__ void stage_rows(const unsigned short* gbase, int ldg,
                                           unsigned short* lds, int tid) {
    int wuni = tid & ~63;
#pragma unroll
    for (int it = 0; it < ROWS / 32; ++it) {
        int s = it * 256 + tid;
        int r = s >> 3, c = s & 7;
        int cc = c ^ (r & 7);  // inverse swizzle on global source; LDS stays gll-linear
        gll16(gbase + (size_t)r * ldg + cc * 8, lds + (size_t)(it * 256 + wuni) * 8);
    }
}

// EPI: 0 bias->bf16 | 1 bias+queries[row&7]->f32 | 2 bias+gelu->bf16 | 3 bias+aux[row]->bf16 | 4 bias->f32
template <int EPI>
__global__ __launch_bounds__(256) void gemm_bf16(
    const unsigned short* __restrict__ A, const unsigned short* __restrict__ W,
    const float* __restrict__ bias, void* __restrict__ out,
    const float* __restrict__ aux, int K, int N) {
    __shared__ __align__(16) unsigned short lA[128 * 64];
    __shared__ __align__(16) unsigned short lB[128 * 64];
    const int tid = threadIdx.x;
    const int l = tid & 63, w = tid >> 6;
    // bijective XCD-aware swizzle (all launch grids have nwg % 8 == 0)
    int gx = gridDim.x;
    int lid = blockIdx.y * gx + blockIdx.x;
    int nwg = gx * gridDim.y;
    int idx = (nwg & 7) ? lid : ((lid & 7) * (nwg >> 3) + (lid >> 3));
    const int bm0 = (idx / gx) * 128, bn0 = (idx % gx) * 128;
    const int wm = (w >> 1) * 64, wn = (w & 1) * 64;
    const int l15 = l & 15, lk = l >> 4;
    f32x4 acc[4][4] = {};
    const int nk = K >> 6;
    const unsigned short* Abase = A + (size_t)bm0 * K;
    const unsigned short* Wbase = W + (size_t)bn0 * K;
    for (int kt = 0; kt < nk; ++kt) {
        stage_rows<128>(Abase + kt * 64, K, lA, tid);
        stage_rows<128>(Wbase + kt * 64, K, lB, tid);
        __syncthreads();
        short8 af[4], bf[4];
#pragma unroll
        for (int kk = 0; kk < 2; ++kk) {
#pragma unroll
            for (int mf = 0; mf < 4; ++mf) {
                int r = wm + mf * 16 + l15;
                int c = (kk * 4 + lk) ^ (r & 7);
                af[mf] = *(const short8*)(lA + r * 64 + c * 8);
            }
#pragma unroll
            for (int nf = 0; nf < 4; ++nf) {
                int r = wn + nf * 16 + l15;
                int c = (kk * 4 + lk) ^ (r & 7);
                bf[nf] = *(const short8*)(lB + r * 64 + c * 8);
            }
#pragma unroll
            for (int mf = 0; mf < 4; ++mf)
#pragma unroll
                for (int nf = 0; nf < 4; ++nf)
                    acc[mf][nf] = __builtin_amdgcn_mfma_f32_16x16x32_bf16(af[mf], bf[nf], acc[mf][nf], 0, 0, 0);
        }
        __syncthreads();
    }
    const int row0 = bm0 + wm + (lk << 2);
    const int col0 = bn0 + wn + l15;
#pragma unroll
    for (int nf = 0; nf < 4; ++nf) {
        int col = col0 + nf * 16;
        float bv = bias[col];
#pragma unroll
        for (int mf = 0; mf < 4; ++mf) {
#pragma unroll
            for (int r = 0; r < 4; ++r) {
                int row = row0 + mf * 16 + r;
                float v = acc[mf][nf][r] + bv;
                size_t idx2 = (size_t)row * N + col;
                if constexpr (EPI == 0) {
                    ((unsigned short*)out)[idx2] = f2b(v);
                } else if constexpr (EPI == 1) {
                    v += aux[(row & 7) * N + col];
                    ((float*)out)[idx2] = v;
                } else if constexpr (EPI == 2) {
                    v = 0.5f * v * (1.0f + erff(v * 0.70710678118f));
                    ((unsigned short*)out)[idx2] = f2b(v);
                } else if constexpr (EPI == 3) {
                    v += aux[idx2];
                    ((unsigned short*)out)[idx2] = f2b(v);
                } else {
                    ((float*)out)[idx2] = v;
                }
            }
        }
    }
}

// ---------------- scores GEMM: S[100352][64] f32 = kv_norm @ qk^T ----------------
__global__ __launch_bounds__(256) void gemm_scores(const unsigned short* __restrict__ A,
                                                   const unsigned short* __restrict__ Qk,
                                                   float* __restrict__ S) {
    __shared__ __align__(16) unsigned short lA[128 * 64];
    __shared__ __align__(16) unsigned short lB[64 * 64];
    const int tid = threadIdx.x;
    const int l = tid & 63, w = tid >> 6;
    int lid = blockIdx.x;
    int idx = (lid & 7) * (gridDim.x >> 3) + (lid >> 3);
    const int bm0 = idx * 128;
    const int wm = (w >> 1) * 64, wn = (w & 1) * 32;
    const int l15 = l & 15, lk = l >> 4;
    f32x4 acc[4][2] = {};
    const unsigned short* Abase = A + (size_t)bm0 * 768;
    for (int kt = 0; kt < 12; ++kt) {
        stage_rows<128>(Abase + kt * 64, 768, lA, tid);
        stage_rows<64>(Qk + kt * 64, 768, lB, tid);
        __syncthreads();
        short8 af[4], bf[2];
#pragma unroll
        for (int kk = 0; kk < 2; ++kk) {
#pragma unroll
            for (int mf = 0; mf < 4; ++mf) {
                int r = wm + mf * 16 + l15;
                int c = (kk * 4 + lk) ^ (r & 7);
                af[mf] = *(const short8*)(lA + r * 64 + c * 8);
            }
#pragma unroll
            for (int nf = 0; nf < 2; ++nf) {
                int r = wn + nf * 16 + l15;
                int c = (kk * 4 + lk) ^ (r & 7);
                bf[nf] = *(const short8*)(lB + r * 64 + c * 8);
            }
#pragma unroll
            for (int mf = 0; mf < 4; ++mf)
#pragma unroll
                for (int nf = 0; nf < 2; ++nf)
                    acc[mf][nf] = __builtin_amdgcn_mfma_f32_16x16x32_bf16(af[mf], bf[nf], acc[mf][nf], 0, 0, 0);
        }
        __syncthreads();
    }
    const int row0 = bm0 + wm + (lk << 2);
    const int col0 = wn + l15;
#pragma unroll
    for (int nf = 0; nf < 2; ++nf)
#pragma unroll
        for (int mf = 0; mf < 4; ++mf)
#pragma unroll
            for (int r = 0; r < 4; ++r)
                S[(size_t)(row0 + mf * 16 + r) * 64 + col0 + nf * 16] = acc[mf][nf][r];
}

// ---------------- attention: softmax(S) @ V per (b,h) ----------------
__global__ __launch_bounds__(64) void attn2(const unsigned short* __restrict__ vp,
                                            const float* __restrict__ S,
                                            unsigned short* __restrict__ ctx) {
    __shared__ __align__(16) unsigned short vt[49 * 96];
    __shared__ float sc[8][50];
    const int b = blockIdx.x >> 3, h = blockIdx.x & 7;
    const int t = threadIdx.x;
    const unsigned short* vbase = vp + (size_t)b * 49 * 768 + h * 96;
    for (int ch = t; ch < 588; ch += 64) {
        int n = ch / 12, cb = ch - n * 12;
        *(ushort8*)(vt + ch * 8) = *(const ushort8*)(vbase + (size_t)n * 768 + cb * 8);
    }
    const float* sbase = S + (size_t)b * 49 * 64 + h * 8;
    for (int i = t; i < 392; i += 64) {
        int n = i >> 3, q = i & 7;
        sc[q][n] = sbase[n * 64 + q];
    }
    __syncthreads();
    if (t < 8) {
        float m = -1e30f;
        for (int n = 0; n < 49; ++n) m = fmaxf(m, sc[t][n]);
        float sum = 0.f;
        for (int n = 0; n < 49; ++n) { float e = __expf(sc[t][n] - m); sc[t][n] = e; sum += e; }
        float inv = 1.0f / sum;
        for (int n = 0; n < 49; ++n) sc[t][n] *= inv;
    }
    __syncthreads();
    const int q = t >> 3;
    unsigned short* orow = ctx + (size_t)(b * 8 + q) * 768 + h * 96;
#pragma unroll
    for (int j = 0; j < 3; ++j) {
        int dbase = ((t & 7) + 8 * j) * 4;
        float a0 = 0, a1 = 0, a2 = 0, a3 = 0;
        for (int n = 0; n < 49; ++n) {
            float a = sc[q][n];
            ushort4 vv = *(const ushort4*)(vt + n * 96 + dbase);
            a0 += a * b2f(vv.x); a1 += a * b2f(vv.y); a2 += a * b2f(vv.z); a3 += a * b2f(vv.w);
        }
        ushort4 o; o.x = f2b(a0); o.y = f2b(a1); o.z = f2b(a2); o.w = f2b(a3);
        *(ushort4*)(orow + dbase) = o;
    }
}

// ---------------- host ----------------
extern "C" void kernel_launch(void* const* d_in, const int* in_sizes, int n_in,
                              void* d_out, int out_size, void* d_ws, size_t ws_size,
                              hipStream_t stream) {
    (void)in_sizes; (void)n_in; (void)out_size;
    const float* features      = (const float*)d_in[0];
    const float* input_proj_w  = (const float*)d_in[1];
    const float* input_proj_b  = (const float*)d_in[2];
    const float* queries       = (const float*)d_in[3];
    const float* ln_q_g        = (const float*)d_in[4];
    const float* ln_q_b        = (const float*)d_in[5];
    const float* ln_kv_g       = (const float*)d_in[6];
    const float* ln_kv_b       = (const float*)d_in[7];
    const float* in_proj_w     = (const float*)d_in[8];
    const float* in_proj_b     = (const float*)d_in[9];
    const float* out_proj_w    = (const float*)d_in[10];
    const float* out_proj_b    = (const float*)d_in[11];
    const float* ln_ff_g       = (const float*)d_in[12];
    const float* ln_ff_b       = (const float*)d_in[13];
    const float* ffn_w1        = (const float*)d_in[14];
    const float* ffn_b1        = (const float*)d_in[15];
    const float* ffn_w2        = (const float*)d_in[16];
    const float* ffn_b2        = (const float*)d_in[17];
    const float* output_proj_w = (const float*)d_in[18];
    const float* output_proj_b = (const float*)d_in[19];
    const float* final_g       = (const float*)d_in[20];
    const float* final_b       = (const float*)d_in[21];

    char* ws = (char*)d_ws;
    size_t off = 0;
    auto alloc = [&](size_t bytes) -> char* {
        char* r = ws + off; off += (bytes + 255) & ~(size_t)255; return r;
    };
    unsigned short* featb = (unsigned short*)alloc(100352ull * 320 * 2);   // 64 MB
    unsigned short* kvbuf = (unsigned short*)alloc(100352ull * 768 * 2);   // 154 MB
    unsigned short* vp    = (unsigned short*)alloc(100352ull * 768 * 2);   // 154 MB
    float*          S     = (float*)alloc(100352ull * 64 * 4);             // 26 MB
    unsigned short* winb  = (unsigned short*)alloc(768ull * 320 * 2);
    unsigned short* wvb   = (unsigned short*)alloc(768ull * 768 * 2);
    unsigned short* woutb = (unsigned short*)alloc(768ull * 768 * 2);
    unsigned short* w1b   = (unsigned short*)alloc(768ull * 768 * 2);
    unsigned short* w2b   = (unsigned short*)alloc(768ull * 768 * 2);
    unsigned short* wopb  = (unsigned short*)alloc(3072ull * 768 * 2);
    float* qnorm          = (float*)alloc(8 * 768 * 4);
    float* qpb            = (float*)alloc(8 * 768 * 4);
    unsigned short* qkb   = (unsigned short*)alloc(64ull * 768 * 2);
    if (off > ws_size) return;  // fail visibly (output stays poisoned)

    // region reuse (dead by the time they're overwritten):
    unsigned short* ctx = featb;                                   // 25 MB <= 64 MB
    float* x            = (float*)vp;                              // vp dead after attn2
    unsigned short* hn  = (unsigned short*)((char*)vp + 50331648);
    unsigned short* f1  = (unsigned short*)((char*)vp + 75497472);
    unsigned short* x2  = (unsigned short*)((char*)vp + 100663296);

    // weight/input casts to bf16
    cast_f2b<<<31360, 256, 0, stream>>>(features, featb, 8028160);
    cast_f2b<<<240,   256, 0, stream>>>(input_proj_w, winb, 61440);
    cast_f2b<<<576,   256, 0, stream>>>(in_proj_w + 2 * 768 * 768, wvb, 147456);  // wv
    cast_f2b<<<576,   256, 0, stream>>>(out_proj_w, woutb, 147456);
    cast_f2b<<<576,   256, 0, stream>>>(ffn_w1, w1b, 147456);
    cast_f2b<<<576,   256, 0, stream>>>(ffn_w2, w2b, 147456);
    cast_f2b<<<2304,  256, 0, stream>>>(output_proj_w, wopb, 589824);

    // batch-independent query path (fp32, tiny)
    ln_rows<768, false, false><<<2, 256, 0, stream>>>(queries, qnorm, ln_q_g, ln_q_b, 8);
    qp_kernel<<<24, 256, 0, stream>>>(qnorm, in_proj_w, in_proj_b, qpb);
    qk_build<<<64, 256, 0, stream>>>(qpb, in_proj_w + 768 * 768, qkb);

    // kv = features @ Win^T + b  -> bf16
    gemm_bf16<0><<<dim3(6, 784), 256, 0, stream>>>(featb, winb, input_proj_b, kvbuf, nullptr, 320, 768);
    // LN(kv) in place
    ln_rows<768, true, true><<<25088, 256, 0, stream>>>(kvbuf, kvbuf, ln_kv_g, ln_kv_b, 100352);
    // S = kv_norm @ qk^T (scaled; bk cancels in softmax)
    gemm_scores<<<784, 256, 0, stream>>>(kvbuf, qkb, S);
    // vp = kv_norm @ wv^T + bv -> bf16
    gemm_bf16<0><<<dim3(6, 784), 256, 0, stream>>>(kvbuf, wvb, in_proj_b + 1536, vp, nullptr, 768, 768);
    // ctx = softmax(S) @ vp
    attn2<<<16384, 64, 0, stream>>>(vp, S, ctx);
    // x = ctx @ out_proj^T + b + queries  -> f32
    gemm_bf16<1><<<dim3(6, 128), 256, 0, stream>>>(ctx, woutb, out_proj_b, x, queries, 768, 768);
    // h = LN(x) -> bf16
    ln_rows<768, false, true><<<4096, 256, 0, stream>>>(x, hn, ln_ff_g, ln_ff_b, 16384);
    // f1 = gelu(h @ w1^T + b1) -> bf16
    gemm_bf16<2><<<dim3(6, 128), 256, 0, stream>>>(hn, w1b, ffn_b1, f1, nullptr, 768, 768);
    // x2 = f1 @ w2^T + b2 + x -> bf16
    gemm_bf16<3><<<dim3(6, 128), 256, 0, stream>>>(f1, w2b, ffn_b2, x2, x, 768, 768);
    // out_pre = x2 @ Wop^T + b -> f32 (into d_out)
    gemm_bf16<4><<<dim3(24, 128), 256, 0, stream>>>(x2, wopb, output_proj_b, d_out, nullptr, 768, 3072);
    // final LN in place on d_out
    ln_rows<3072, false, false><<<4096, 256, 0, stream>>>((float*)d_out, (float*)d_out, final_g, final_b, 16384);
}

// Round 3
// 816.451 us; speedup vs baseline: 1.4296x; 1.1549x over previous
//
#include <hip/hip_runtime.h>
#include <math.h>

typedef __attribute__((ext_vector_type(8))) short short8;
typedef __attribute__((ext_vector_type(8))) unsigned short ushort8;
typedef __attribute__((ext_vector_type(4))) float f32x4;

__device__ __forceinline__ float b2f(unsigned short h) {
    union { unsigned int u; float f; } c; c.u = ((unsigned int)h) << 16; return c.f;
}
__device__ __forceinline__ unsigned short f2b(float x) {
    union { float f; unsigned int u; } c; c.f = x;
    unsigned int r = c.u + 0x7fffu + ((c.u >> 16) & 1u);
    return (unsigned short)(r >> 16);
}

// ---------------- cast f32 -> bf16 (vectorized) ----------------
__global__ __launch_bounds__(256) void cast_f2b(const float* __restrict__ in,
                                                unsigned short* __restrict__ out, int n4) {
    int i = blockIdx.x * 256 + threadIdx.x;
    if (i >= n4) return;
    float4 f = ((const float4*)in)[i];
    ushort4 o; o.x = f2b(f.x); o.y = f2b(f.y); o.z = f2b(f.z); o.w = f2b(f.w);
    ((ushort4*)out)[i] = o;
}

// ---------------- wave-per-row LayerNorm ----------------
template <int DD, bool INB, bool OUTB>
__global__ __launch_bounds__(256) void ln_rows(const void* __restrict__ in_, void* __restrict__ out_,
                                               const float* __restrict__ g, const float* __restrict__ bb,
                                               int nrows) {
    const int wv = threadIdx.x >> 6, l = threadIdx.x & 63;
    const int row = blockIdx.x * 4 + wv;
    if (row >= nrows) return;
    constexpr int NC = DD / 256;
    float v[DD / 64];
    if constexpr (INB) {
        const ushort4* in = (const ushort4*)((const unsigned short*)in_ + (size_t)row * DD);
#pragma unroll
        for (int c = 0; c < NC; ++c) {
            ushort4 u = in[l + 64 * c];
            v[4*c] = b2f(u.x); v[4*c+1] = b2f(u.y); v[4*c+2] = b2f(u.z); v[4*c+3] = b2f(u.w);
        }
    } else {
        const float4* in = (const float4*)((const float*)in_ + (size_t)row * DD);
#pragma unroll
        for (int c = 0; c < NC; ++c) {
            float4 u = in[l + 64 * c];
            v[4*c] = u.x; v[4*c+1] = u.y; v[4*c+2] = u.z; v[4*c+3] = u.w;
        }
    }
    float s = 0.f, s2 = 0.f;
#pragma unroll
    for (int i = 0; i < DD / 64; ++i) { s += v[i]; s2 += v[i] * v[i]; }
#pragma unroll
    for (int o = 32; o > 0; o >>= 1) { s += __shfl_xor(s, o, 64); s2 += __shfl_xor(s2, o, 64); }
    const float mu = s * (1.0f / DD);
    const float var = s2 * (1.0f / DD) - mu * mu;
    const float rs = rsqrtf(var + 1e-5f);
    if constexpr (OUTB) {
        ushort4* out = (ushort4*)((unsigned short*)out_ + (size_t)row * DD);
#pragma unroll
        for (int c = 0; c < NC; ++c) {
            int e = (l + 64 * c) * 4;
            ushort4 o4;
            o4.x = f2b((v[4*c]   - mu) * rs * g[e]   + bb[e]);
            o4.y = f2b((v[4*c+1] - mu) * rs * g[e+1] + bb[e+1]);
            o4.z = f2b((v[4*c+2] - mu) * rs * g[e+2] + bb[e+2]);
            o4.w = f2b((v[4*c+3] - mu) * rs * g[e+3] + bb[e+3]);
            out[l + 64 * c] = o4;
        }
    } else {
        float4* out = (float4*)((float*)out_ + (size_t)row * DD);
#pragma unroll
        for (int c = 0; c < NC; ++c) {
            int e = (l + 64 * c) * 4;
            float4 o4;
            o4.x = (v[4*c]   - mu) * rs * g[e]   + bb[e];
            o4.y = (v[4*c+1] - mu) * rs * g[e+1] + bb[e+1];
            o4.z = (v[4*c+2] - mu) * rs * g[e+2] + bb[e+2];
            o4.w = (v[4*c+3] - mu) * rs * g[e+3] + bb[e+3];
            out[l + 64 * c] = o4;
        }
    }
}

// ---------------- qp = LN(queries) @ wq^T + bq ----------------
__global__ __launch_bounds__(256) void qp_kernel(const float* __restrict__ qn, const float* __restrict__ wq,
                                                 const float* __restrict__ bq, float* __restrict__ qp) {
    int q = blockIdx.x / 3;
    int col = (blockIdx.x % 3) * 256 + threadIdx.x;
    const float4* a = (const float4*)(qn + q * 768);
    const float4* wr = (const float4*)(wq + (size_t)col * 768);
    float s = 0.f;
#pragma unroll 8
    for (int k = 0; k < 192; ++k) {
        float4 xx = a[k], yy = wr[k];
        s += xx.x * yy.x + xx.y * yy.y + xx.z * yy.z + xx.w * yy.w;
    }
    qp[q * 768 + col] = s + bq[col];
}

// ---------------- qk[hq][e] = scale * sum_d qp[q][h*96+d] * wk[h*96+d][e] ----------------
__global__ __launch_bounds__(256) void qk_build(const float* __restrict__ qp, const float* __restrict__ wk,
                                                unsigned short* __restrict__ qk) {
    const int hq = blockIdx.x, h = hq >> 3, q = hq & 7;
    const float* qv = qp + q * 768 + h * 96;
#pragma unroll
    for (int c = 0; c < 3; ++c) {
        int e = threadIdx.x + 256 * c;
        float s = 0.f;
        for (int d = 0; d < 96; ++d) s += qv[d] * wk[(size_t)(h * 96 + d) * 768 + e];
        qk[hq * 768 + e] = f2b(s * 0.10206207262f);
    }
}

// ---------------- MFMA GEMM machinery ----------------
__device__ __forceinline__ void gll16(const void* g, void* l) {
    __builtin_amdgcn_global_load_lds((const __attribute__((address_space(1))) unsigned int*)g,
                                     (__attribute__((address_space(3))) unsigned int*)l, 16, 0, 0);
}

template <int ROWS>
__device__ __forceinline__ void stage_rows(const unsigned short* gbase, int ldg,
                                           unsigned short* lds, int tid) {
    int wuni = tid & ~63;
#pragma unroll
    for (int it = 0; it < ROWS / 32; ++it) {
        int s = it * 256 + tid;
        int r = s >> 3, c = s & 7;
        int cc = c ^ (r & 7);  // inverse swizzle on global source; LDS stays gll-linear
        gll16(gbase + (size_t)r * ldg + cc * 8, lds + (size_t)(it * 256 + wuni) * 8);
    }
}

// EPI: 0 bias->bf16 | 1 bias+queries[row&7]->f32 | 2 bias+gelu->bf16 | 3 bias+aux[row]->bf16 | 4 bias->f32
template <int EPI>
__global__ __launch_bounds__(256) void gemm_bf16(
    const unsigned short* __restrict__ A, const unsigned short* __restrict__ W,
    const float* __restrict__ bias, void* __restrict__ out,
    const float* __restrict__ aux, int K, int N) {
    __shared__ __align__(16) unsigned short lA[128 * 64];
    __shared__ __align__(16) unsigned short lB[128 * 64];
    const int tid = threadIdx.x;
    const int l = tid & 63, w = tid >> 6;
    int gx = gridDim.x;
    int lid = blockIdx.y * gx + blockIdx.x;
    int nwg = gx * gridDim.y;
    int idx = (nwg & 7) ? lid : ((lid & 7) * (nwg >> 3) + (lid >> 3));
    const int bm0 = (idx / gx) * 128, bn0 = (idx % gx) * 128;
    const int wm = (w >> 1) * 64, wn = (w & 1) * 64;
    const int l15 = l & 15, lk = l >> 4;
    f32x4 acc[4][4] = {};
    const int nk = K >> 6;
    const unsigned short* Abase = A + (size_t)bm0 * K;
    const unsigned short* Wbase = W + (size_t)bn0 * K;
    for (int kt = 0; kt < nk; ++kt) {
        stage_rows<128>(Abase + kt * 64, K, lA, tid);
        stage_rows<128>(Wbase + kt * 64, K, lB, tid);
        __syncthreads();
        short8 af[4], bf[4];
#pragma unroll
        for (int kk = 0; kk < 2; ++kk) {
#pragma unroll
            for (int mf = 0; mf < 4; ++mf) {
                int r = wm + mf * 16 + l15;
                int c = (kk * 4 + lk) ^ (r & 7);
                af[mf] = *(const short8*)(lA + r * 64 + c * 8);
            }
#pragma unroll
            for (int nf = 0; nf < 4; ++nf) {
                int r = wn + nf * 16 + l15;
                int c = (kk * 4 + lk) ^ (r & 7);
                bf[nf] = *(const short8*)(lB + r * 64 + c * 8);
            }
#pragma unroll
            for (int mf = 0; mf < 4; ++mf)
#pragma unroll
                for (int nf = 0; nf < 4; ++nf)
                    acc[mf][nf] = __builtin_amdgcn_mfma_f32_16x16x32_bf16(af[mf], bf[nf], acc[mf][nf], 0, 0, 0);
        }
        __syncthreads();
    }
    const int row0 = bm0 + wm + (lk << 2);
    const int col0 = bn0 + wn + l15;
#pragma unroll
    for (int nf = 0; nf < 4; ++nf) {
        int col = col0 + nf * 16;
        float bv = bias[col];
#pragma unroll
        for (int mf = 0; mf < 4; ++mf) {
#pragma unroll
            for (int r = 0; r < 4; ++r) {
                int row = row0 + mf * 16 + r;
                float v = acc[mf][nf][r] + bv;
                size_t idx2 = (size_t)row * N + col;
                if constexpr (EPI == 0) {
                    ((unsigned short*)out)[idx2] = f2b(v);
                } else if constexpr (EPI == 1) {
                    v += aux[(row & 7) * N + col];
                    ((float*)out)[idx2] = v;
                } else if constexpr (EPI == 2) {
                    v = 0.5f * v * (1.0f + erff(v * 0.70710678118f));
                    ((unsigned short*)out)[idx2] = f2b(v);
                } else if constexpr (EPI == 3) {
                    v += aux[idx2];
                    ((unsigned short*)out)[idx2] = f2b(v);
                } else {
                    ((float*)out)[idx2] = v;
                }
            }
        }
    }
}

// ---------------- scores GEMM: S[100352][64] f32 = kv_norm @ qk^T ----------------
__global__ __launch_bounds__(256) void gemm_scores(const unsigned short* __restrict__ A,
                                                   const unsigned short* __restrict__ Qk,
                                                   float* __restrict__ S) {
    __shared__ __align__(16) unsigned short lA[128 * 64];
    __shared__ __align__(16) unsigned short lB[64 * 64];
    const int tid = threadIdx.x;
    const int l = tid & 63, w = tid >> 6;
    int lid = blockIdx.x;
    int idx = (lid & 7) * (gridDim.x >> 3) + (lid >> 3);
    const int bm0 = idx * 128;
    const int wm = (w >> 1) * 64, wn = (w & 1) * 32;
    const int l15 = l & 15, lk = l >> 4;
    f32x4 acc[4][2] = {};
    const unsigned short* Abase = A + (size_t)bm0 * 768;
    for (int kt = 0; kt < 12; ++kt) {
        stage_rows<128>(Abase + kt * 64, 768, lA, tid);
        stage_rows<64>(Qk + kt * 64, 768, lB, tid);
        __syncthreads();
        short8 af[4], bf[2];
#pragma unroll
        for (int kk = 0; kk < 2; ++kk) {
#pragma unroll
            for (int mf = 0; mf < 4; ++mf) {
                int r = wm + mf * 16 + l15;
                int c = (kk * 4 + lk) ^ (r & 7);
                af[mf] = *(const short8*)(lA + r * 64 + c * 8);
            }
#pragma unroll
            for (int nf = 0; nf < 2; ++nf) {
                int r = wn + nf * 16 + l15;
                int c = (kk * 4 + lk) ^ (r & 7);
                bf[nf] = *(const short8*)(lB + r * 64 + c * 8);
            }
#pragma unroll
            for (int mf = 0; mf < 4; ++mf)
#pragma unroll
                for (int nf = 0; nf < 2; ++nf)
                    acc[mf][nf] = __builtin_amdgcn_mfma_f32_16x16x32_bf16(af[mf], bf[nf], acc[mf][nf], 0, 0, 0);
        }
        __syncthreads();
    }
    const int row0 = bm0 + wm + (lk << 2);
    const int col0 = wn + l15;
#pragma unroll
    for (int nf = 0; nf < 2; ++nf)
#pragma unroll
        for (int mf = 0; mf < 4; ++mf)
#pragma unroll
            for (int r = 0; r < 4; ++r)
                S[(size_t)(row0 + mf * 16 + r) * 64 + col0 + nf * 16] = acc[mf][nf][r];
}

// ---------------- attn_mix: per b, softmax(S[b]) then cmix[h][b*8+q][e] = attn @ kv_norm[b] ----
// attn in LDS [64 hq][64 n] (chunk-swizzled, n>=49 zero); kv_norm[b] staged TRANSPOSED
// kvT[e_local][n] (chunk-swizzled) in two e-halves of 384 so LDS stays <= 56 KB.
__global__ __launch_bounds__(256) void attn_mix(const unsigned short* __restrict__ kvn,
                                                const float* __restrict__ S,
                                                unsigned short* __restrict__ cmix) {
    __shared__ __align__(16) unsigned short at[64 * 64];      // 8 KB
    __shared__ __align__(16) unsigned short kvT[384 * 64];    // 48 KB; Sl unions into it
    float* Sl = (float*)kvT;                                  // 49*64 f32 = 12.25 KB, dead before kvT use
    const int b = blockIdx.x;
    const int t = threadIdx.x, l = t & 63, w = t >> 6;
    const int l15 = l & 15, lk = l >> 4;

    for (int i = t; i < 3136; i += 256) Sl[i] = S[(size_t)b * 3136 + i];
    __syncthreads();
    if (w == 0) {
        float mx = -1e30f;
        for (int n = 0; n < 49; ++n) mx = fmaxf(mx, Sl[n * 64 + l]);
        float sum = 0.f;
        for (int n = 0; n < 49; ++n) sum += __expf(Sl[n * 64 + l] - mx);
        float inv = 1.0f / sum;
#pragma unroll
        for (int c = 0; c < 8; ++c) {
            int cc = c ^ (l & 7);
            for (int j = 0; j < 8; ++j) {
                int n = c * 8 + j;
                float a = (n < 49) ? __expf(Sl[n * 64 + l] - mx) * inv : 0.f;
                at[l * 64 + cc * 8 + j] = f2b(a);
            }
        }
    }
    __syncthreads();  // softmax done reading Sl; kvT may now overwrite it

    const unsigned short* src = kvn + ((size_t)b * 49 + (l < 49 ? l : 0)) * 768;
#pragma unroll 1
    for (int half = 0; half < 2; ++half) {
        // stage kvT[e][n], e in [half*384, half*384+384), zero rows n>=49 (NaN guard)
        for (int i = 0; i < 12; ++i) {
            int e0 = w * 8 + i * 32;  // local e
            ushort8 v = {0, 0, 0, 0, 0, 0, 0, 0};
            if (l < 49) v = *(const ushort8*)(src + half * 384 + e0);
#pragma unroll
            for (int j = 0; j < 8; ++j) {
                int e = e0 + j;
                kvT[e * 64 + (((l >> 3) ^ (e & 7)) << 3) + (l & 7)] = v[j];
            }
        }
        __syncthreads();
        // mix MFMA: wave w owns local e in [w*96, w*96+96), two chunks of 48
#pragma unroll 1
        for (int c2 = 0; c2 < 2; ++c2) {
            int ebase = w * 96 + c2 * 48;
            f32x4 acc[4][3] = {};
#pragma unroll
            for (int ks = 0; ks < 2; ++ks) {
                short8 af[4], bf[3];
#pragma unroll
                for (int mf = 0; mf < 4; ++mf) {
                    int r = mf * 16 + l15;
                    af[mf] = *(const short8*)(at + r * 64 + (((ks * 4 + lk) ^ (r & 7)) << 3));
                }
#pragma unroll
                for (int nf = 0; nf < 3; ++nf) {
                    int er = ebase + nf * 16 + l15;
                    bf[nf] = *(const short8*)(kvT + er * 64 + (((ks * 4 + lk) ^ (er & 7)) << 3));
                }
#pragma unroll
                for (int mf = 0; mf < 4; ++mf)
#pragma unroll
                    for (int nf = 0; nf < 3; ++nf)
                        acc[mf][nf] = __builtin_amdgcn_mfma_f32_16x16x32_bf16(af[mf], bf[nf], acc[mf][nf], 0, 0, 0);
            }
#pragma unroll
            for (int mf = 0; mf < 4; ++mf)
#pragma unroll
                for (int nf = 0; nf < 3; ++nf)
#pragma unroll
                    for (int r = 0; r < 4; ++r) {
                        int hq = mf * 16 + lk * 4 + r;
                        int e = half * 384 + ebase + nf * 16 + l15;
                        cmix[((size_t)(hq >> 3) * 16384 + b * 8 + (hq & 7)) * 768 + e] = f2b(acc[mf][nf][r]);
                    }
        }
        __syncthreads();  // mix reads done before next half restages kvT
    }
}

// ---------------- gemm_ctx: per-h ctx = cmix_h @ wv_h^T + bv_h (16384 x 96, K=768) ----------------
__global__ __launch_bounds__(256) void gemm_ctx(const unsigned short* __restrict__ cmix,
                                                const unsigned short* __restrict__ wvb,
                                                const float* __restrict__ bv,
                                                unsigned short* __restrict__ ctx) {
    __shared__ __align__(16) unsigned short lA[128 * 64];
    __shared__ __align__(16) unsigned short lB[128 * 64];
    const int tid = threadIdx.x;
    const int l = tid & 63, w = tid >> 6;
    const int h = blockIdx.z;
    int yy = blockIdx.y;
    int idx = (yy & 7) * 16 + (yy >> 3);
    const int bm0 = idx * 128;
    const int wm = (w >> 1) * 64, wn = (w & 1) * 64;
    const int l15 = l & 15, lk = l >> 4;
    f32x4 acc[4][4] = {};
    const unsigned short* Abase = cmix + (size_t)h * 16384 * 768 + (size_t)bm0 * 768;
    const unsigned short* Wbase = wvb + (size_t)h * 96 * 768;  // rows 96..127 over-read: allocated scratch
    for (int kt = 0; kt < 12; ++kt) {
        stage_rows<128>(Abase + kt * 64, 768, lA, tid);
        stage_rows<128>(Wbase + kt * 64, 768, lB, tid);
        __syncthreads();
        short8 af[4], bf[4];
#pragma unroll
        for (int kk = 0; kk < 2; ++kk) {
#pragma unroll
            for (int mf = 0; mf < 4; ++mf) {
                int r = wm + mf * 16 + l15;
                int c = (kk * 4 + lk) ^ (r & 7);
                af[mf] = *(const short8*)(lA + r * 64 + c * 8);
            }
#pragma unroll
            for (int nf = 0; nf < 4; ++nf) {
                int r = wn + nf * 16 + l15;
                int c = (kk * 4 + lk) ^ (r & 7);
                bf[nf] = *(const short8*)(lB + r * 64 + c * 8);
            }
#pragma unroll
            for (int mf = 0; mf < 4; ++mf)
#pragma unroll
                for (int nf = 0; nf < 4; ++nf)
                    acc[mf][nf] = __builtin_amdgcn_mfma_f32_16x16x32_bf16(af[mf], bf[nf], acc[mf][nf], 0, 0, 0);
        }
        __syncthreads();
    }
    const int row0 = bm0 + wm + (lk << 2);
    const int col0 = wn + l15;
#pragma unroll
    for (int nf = 0; nf < 4; ++nf) {
        int col = col0 + nf * 16;
        if (col >= 96) continue;
        float bvv = bv[h * 96 + col];
#pragma unroll
        for (int mf = 0; mf < 4; ++mf)
#pragma unroll
            for (int r = 0; r < 4; ++r) {
                int row = row0 + mf * 16 + r;
                ctx[(size_t)row * 768 + h * 96 + col] = f2b(acc[mf][nf][r] + bvv);
            }
    }
}

// ---------------- host ----------------
extern "C" void kernel_launch(void* const* d_in, const int* in_sizes, int n_in,
                              void* d_out, int out_size, void* d_ws, size_t ws_size,
                              hipStream_t stream) {
    (void)in_sizes; (void)n_in; (void)out_size;
    const float* features      = (const float*)d_in[0];
    const float* input_proj_w  = (const float*)d_in[1];
    const float* input_proj_b  = (const float*)d_in[2];
    const float* queries       = (const float*)d_in[3];
    const float* ln_q_g        = (const float*)d_in[4];
    const float* ln_q_b        = (const float*)d_in[5];
    const float* ln_kv_g       = (const float*)d_in[6];
    const float* ln_kv_b       = (const float*)d_in[7];
    const float* in_proj_w     = (const float*)d_in[8];
    const float* in_proj_b     = (const float*)d_in[9];
    const float* out_proj_w    = (const float*)d_in[10];
    const float* out_proj_b    = (const float*)d_in[11];
    const float* ln_ff_g       = (const float*)d_in[12];
    const float* ln_ff_b       = (const float*)d_in[13];
    const float* ffn_w1        = (const float*)d_in[14];
    const float* ffn_b1        = (const float*)d_in[15];
    const float* ffn_w2        = (const float*)d_in[16];
    const float* ffn_b2        = (const float*)d_in[17];
    const float* output_proj_w = (const float*)d_in[18];
    const float* output_proj_b = (const float*)d_in[19];
    const float* final_g       = (const float*)d_in[20];
    const float* final_b       = (const float*)d_in[21];

    char* ws = (char*)d_ws;
    size_t off = 0;
    auto alloc = [&](size_t bytes) -> char* {
        char* r = ws + off; off += (bytes + 255) & ~(size_t)255; return r;
    };
    unsigned short* featb = (unsigned short*)alloc(100352ull * 320 * 2);    // 64 MB
    unsigned short* kvbuf = (unsigned short*)alloc(100352ull * 768 * 2);    // 154 MB
    unsigned short* cmix  = (unsigned short*)alloc(8ull * 16384 * 768 * 2); // 201 MB
    float*          S     = (float*)alloc(100352ull * 64 * 4);              // 26 MB
    unsigned short* winb  = (unsigned short*)alloc(768ull * 320 * 2);
    unsigned short* wvb   = (unsigned short*)alloc(768ull * 768 * 2);
    unsigned short* woutb = (unsigned short*)alloc(768ull * 768 * 2);
    unsigned short* w1b   = (unsigned short*)alloc(768ull * 768 * 2);
    unsigned short* w2b   = (unsigned short*)alloc(768ull * 768 * 2);
    unsigned short* wopb  = (unsigned short*)alloc(3072ull * 768 * 2);
    float* qnorm          = (float*)alloc(8 * 768 * 4);
    float* qpb            = (float*)alloc(8 * 768 * 4);
    unsigned short* qkb   = (unsigned short*)alloc(64ull * 768 * 2);
    if (off > ws_size) return;  // fail visibly (output stays poisoned)

    // region reuse (dead by the time they're overwritten):
    unsigned short* ctx = featb;                                   // 25 MB <= 64 MB
    float* x            = (float*)cmix;                            // cmix dead after gemm_ctx
    unsigned short* hn  = (unsigned short*)((char*)cmix + 50331648);
    unsigned short* f1  = (unsigned short*)((char*)cmix + 75497472);
    unsigned short* x2  = (unsigned short*)((char*)cmix + 100663296);

    // weight/input casts to bf16
    cast_f2b<<<31360, 256, 0, stream>>>(features, featb, 8028160);
    cast_f2b<<<240,   256, 0, stream>>>(input_proj_w, winb, 61440);
    cast_f2b<<<576,   256, 0, stream>>>(in_proj_w + 2 * 768 * 768, wvb, 147456);  // wv
    cast_f2b<<<576,   256, 0, stream>>>(out_proj_w, woutb, 147456);
    cast_f2b<<<576,   256, 0, stream>>>(ffn_w1, w1b, 147456);
    cast_f2b<<<576,   256, 0, stream>>>(ffn_w2, w2b, 147456);
    cast_f2b<<<2304,  256, 0, stream>>>(output_proj_w, wopb, 589824);

    // batch-independent query path (fp32, tiny)
    ln_rows<768, false, false><<<2, 256, 0, stream>>>(queries, qnorm, ln_q_g, ln_q_b, 8);
    qp_kernel<<<24, 256, 0, stream>>>(qnorm, in_proj_w, in_proj_b, qpb);
    qk_build<<<64, 256, 0, stream>>>(qpb, in_proj_w + 768 * 768, qkb);

    // kv = features @ Win^T + b  -> bf16
    gemm_bf16<0><<<dim3(6, 784), 256, 0, stream>>>(featb, winb, input_proj_b, kvbuf, nullptr, 320, 768);
    // LN(kv) in place
    ln_rows<768, true, true><<<25088, 256, 0, stream>>>(kvbuf, kvbuf, ln_kv_g, ln_kv_b, 100352);
    // S = kv_norm @ qk^T (scaled; bk cancels in softmax)
    gemm_scores<<<784, 256, 0, stream>>>(kvbuf, qkb, S);
    // cmix[h][bq][e] = softmax(S) @ kv_norm
    attn_mix<<<2048, 256, 0, stream>>>(kvbuf, S, cmix);
    // ctx = cmix @ wv^T + bv (per h; Σattn=1 makes bias exact)
    gemm_ctx<<<dim3(1, 128, 8), 256, 0, stream>>>(cmix, wvb, in_proj_b + 1536, ctx);
    // x = ctx @ out_proj^T + b + queries  -> f32
    gemm_bf16<1><<<dim3(6, 128), 256, 0, stream>>>(ctx, woutb, out_proj_b, x, queries, 768, 768);
    // h = LN(x) -> bf16
    ln_rows<768, false, true><<<4096, 256, 0, stream>>>(x, hn, ln_ff_g, ln_ff_b, 16384);
    // f1 = gelu(h @ w1^T + b1) -> bf16
    gemm_bf16<2><<<dim3(6, 128), 256, 0, stream>>>(hn, w1b, ffn_b1, f1, nullptr, 768, 768);
    // x2 = f1 @ w2^T + b2 + x -> bf16
    gemm_bf16<3><<<dim3(6, 128), 256, 0, stream>>>(f1, w2b, ffn_b2, x2, x, 768, 768);
    // out_pre = x2 @ Wop^T + b -> f32 (into d_out)
    gemm_bf16<4><<<dim3(24, 128), 256, 0, stream>>>(x2, wopb, output_proj_b, d_out, nullptr, 768, 3072);
    // final LN in place on d_out
    ln_rows<3072, false, false><<<4096, 256, 0, stream>>>((float*)d_out, (float*)d_out, final_g, final_b, 16384);
}

// Round 4
// 776.287 us; speedup vs baseline: 1.5036x; 1.0517x over previous
//
#include <hip/hip_runtime.h>
#include <math.h>

typedef __attribute__((ext_vector_type(8))) short short8;
typedef __attribute__((ext_vector_type(8))) unsigned short ushort8;
typedef __attribute__((ext_vector_type(4))) float f32x4;

__device__ __forceinline__ float b2f(unsigned short h) {
    union { unsigned int u; float f; } c; c.u = ((unsigned int)h) << 16; return c.f;
}
__device__ __forceinline__ unsigned short f2b(float x) {
    union { float f; unsigned int u; } c; c.f = x;
    unsigned int r = c.u + 0x7fffu + ((c.u >> 16) & 1u);
    return (unsigned short)(r >> 16);
}

// ---------------- cast f32 -> bf16 (vectorized) ----------------
__global__ __launch_bounds__(256) void cast_f2b(const float* __restrict__ in,
                                                unsigned short* __restrict__ out, int n4) {
    int i = blockIdx.x * 256 + threadIdx.x;
    if (i >= n4) return;
    float4 f = ((const float4*)in)[i];
    ushort4 o; o.x = f2b(f.x); o.y = f2b(f.y); o.z = f2b(f.z); o.w = f2b(f.w);
    ((ushort4*)out)[i] = o;
}

// ---------------- wave-per-row LayerNorm ----------------
template <int DD, bool INB, bool OUTB>
__global__ __launch_bounds__(256) void ln_rows(const void* __restrict__ in_, void* __restrict__ out_,
                                               const float* __restrict__ g, const float* __restrict__ bb,
                                               int nrows) {
    const int wv = threadIdx.x >> 6, l = threadIdx.x & 63;
    const int row = blockIdx.x * 4 + wv;
    if (row >= nrows) return;
    constexpr int NC = DD / 256;
    float v[DD / 64];
    if constexpr (INB) {
        const ushort4* in = (const ushort4*)((const unsigned short*)in_ + (size_t)row * DD);
#pragma unroll
        for (int c = 0; c < NC; ++c) {
            ushort4 u = in[l + 64 * c];
            v[4*c] = b2f(u.x); v[4*c+1] = b2f(u.y); v[4*c+2] = b2f(u.z); v[4*c+3] = b2f(u.w);
        }
    } else {
        const float4* in = (const float4*)((const float*)in_ + (size_t)row * DD);
#pragma unroll
        for (int c = 0; c < NC; ++c) {
            float4 u = in[l + 64 * c];
            v[4*c] = u.x; v[4*c+1] = u.y; v[4*c+2] = u.z; v[4*c+3] = u.w;
        }
    }
    float s = 0.f, s2 = 0.f;
#pragma unroll
    for (int i = 0; i < DD / 64; ++i) { s += v[i]; s2 += v[i] * v[i]; }
#pragma unroll
    for (int o = 32; o > 0; o >>= 1) { s += __shfl_xor(s, o, 64); s2 += __shfl_xor(s2, o, 64); }
    const float mu = s * (1.0f / DD);
    const float var = s2 * (1.0f / DD) - mu * mu;
    const float rs = rsqrtf(var + 1e-5f);
    if constexpr (OUTB) {
        ushort4* out = (ushort4*)((unsigned short*)out_ + (size_t)row * DD);
#pragma unroll
        for (int c = 0; c < NC; ++c) {
            int e = (l + 64 * c) * 4;
            ushort4 o4;
            o4.x = f2b((v[4*c]   - mu) * rs * g[e]   + bb[e]);
            o4.y = f2b((v[4*c+1] - mu) * rs * g[e+1] + bb[e+1]);
            o4.z = f2b((v[4*c+2] - mu) * rs * g[e+2] + bb[e+2]);
            o4.w = f2b((v[4*c+3] - mu) * rs * g[e+3] + bb[e+3]);
            out[l + 64 * c] = o4;
        }
    } else {
        float4* out = (float4*)((float*)out_ + (size_t)row * DD);
#pragma unroll
        for (int c = 0; c < NC; ++c) {
            int e = (l + 64 * c) * 4;
            float4 o4;
            o4.x = (v[4*c]   - mu) * rs * g[e]   + bb[e];
            o4.y = (v[4*c+1] - mu) * rs * g[e+1] + bb[e+1];
            o4.z = (v[4*c+2] - mu) * rs * g[e+2] + bb[e+2];
            o4.w = (v[4*c+3] - mu) * rs * g[e+3] + bb[e+3];
            out[l + 64 * c] = o4;
        }
    }
}

// ---------------- ln_stats: per-row (rs, rs*mu) of raw bf16 kv ----------------
__global__ __launch_bounds__(256) void ln_stats(const unsigned short* __restrict__ kv,
                                                float2* __restrict__ stats, int nrows) {
    const int wv = threadIdx.x >> 6, l = threadIdx.x & 63;
    const int row = blockIdx.x * 4 + wv;
    if (row >= nrows) return;
    const ushort4* in = (const ushort4*)(kv + (size_t)row * 768);
    float s = 0.f, s2 = 0.f;
#pragma unroll
    for (int c = 0; c < 3; ++c) {
        ushort4 u = in[l + 64 * c];
        float a = b2f(u.x), b = b2f(u.y), cc = b2f(u.z), d = b2f(u.w);
        s += a + b + cc + d;
        s2 += a * a + b * b + cc * cc + d * d;
    }
#pragma unroll
    for (int o = 32; o > 0; o >>= 1) { s += __shfl_xor(s, o, 64); s2 += __shfl_xor(s2, o, 64); }
    const float mu = s * (1.0f / 768.0f);
    const float var = s2 * (1.0f / 768.0f) - mu * mu;
    const float rs = rsqrtf(var + 1e-5f);
    if (l == 0) stats[row] = make_float2(rs, rs * mu);
}

// ---------------- qp = LN(queries) @ wq^T + bq ----------------
__global__ __launch_bounds__(256) void qp_kernel(const float* __restrict__ qn, const float* __restrict__ wq,
                                                 const float* __restrict__ bq, float* __restrict__ qp) {
    int q = blockIdx.x / 3;
    int col = (blockIdx.x % 3) * 256 + threadIdx.x;
    const float4* a = (const float4*)(qn + q * 768);
    const float4* wr = (const float4*)(wq + (size_t)col * 768);
    float s = 0.f;
#pragma unroll 8
    for (int k = 0; k < 192; ++k) {
        float4 xx = a[k], yy = wr[k];
        s += xx.x * yy.x + xx.y * yy.y + xx.z * yy.z + xx.w * yy.w;
    }
    qp[q * 768 + col] = s + bq[col];
}

// ---------------- qkg[hq][e] = g[e]*scale*sum_d qp[..]*wk[..][e]; t[hq] = sum_e qkg ----------------
// bk and the beta-dot-qk term are constant over n -> cancel in softmax.
__global__ __launch_bounds__(256) void qk_build(const float* __restrict__ qp, const float* __restrict__ wk,
                                                const float* __restrict__ g,
                                                unsigned short* __restrict__ qkg, float* __restrict__ tout) {
    __shared__ float red[4];
    const int hq = blockIdx.x, h = hq >> 3, q = hq & 7;
    const int tid = threadIdx.x;
    const float* qv = qp + q * 768 + h * 96;
    float tsum = 0.f;
#pragma unroll
    for (int c = 0; c < 3; ++c) {
        int e = tid + 256 * c;
        float s = 0.f;
        for (int d = 0; d < 96; ++d) s += qv[d] * wk[(size_t)(h * 96 + d) * 768 + e];
        unsigned short bv = f2b(s * 0.10206207262f * g[e]);
        qkg[hq * 768 + e] = bv;
        tsum += b2f(bv);
    }
#pragma unroll
    for (int o = 32; o > 0; o >>= 1) tsum += __shfl_xor(tsum, o, 64);
    if ((tid & 63) == 0) red[tid >> 6] = tsum;
    __syncthreads();
    if (tid == 0) tout[hq] = red[0] + red[1] + red[2] + red[3];
}

// ---------------- MFMA GEMM machinery ----------------
__device__ __forceinline__ void gll16(const void* g, void* l) {
    __builtin_amdgcn_global_load_lds((const __attribute__((address_space(1))) unsigned int*)g,
                                     (__attribute__((address_space(3))) unsigned int*)l, 16, 0, 0);
}

template <int ROWS>
__device__ __forceinline__ void stage_rows(const unsigned short* gbase, int ldg,
                                           unsigned short* lds, int tid) {
    int wuni = tid & ~63;
#pragma unroll
    for (int it = 0; it < ROWS / 32; ++it) {
        int s = it * 256 + tid;
        int r = s >> 3, c = s & 7;
        int cc = c ^ (r & 7);  // inverse swizzle on global source; LDS stays gll-linear
        gll16(gbase + (size_t)r * ldg + cc * 8, lds + (size_t)(it * 256 + wuni) * 8);
    }
}

// EPI: 0 bias->bf16 | 1 bias+queries[row&7]->f32 | 2 bias+gelu->bf16 | 3 bias+aux[row]->bf16 | 4 bias->f32
template <int EPI>
__global__ __launch_bounds__(256) void gemm_bf16(
    const unsigned short* __restrict__ A, const unsigned short* __restrict__ W,
    const float* __restrict__ bias, void* __restrict__ out,
    const float* __restrict__ aux, int K, int N) {
    __shared__ __align__(16) unsigned short lA[128 * 64];
    __shared__ __align__(16) unsigned short lB[128 * 64];
    const int tid = threadIdx.x;
    const int l = tid & 63, w = tid >> 6;
    int gx = gridDim.x;
    int lid = blockIdx.y * gx + blockIdx.x;
    int nwg = gx * gridDim.y;
    int idx = (nwg & 7) ? lid : ((lid & 7) * (nwg >> 3) + (lid >> 3));
    const int bm0 = (idx / gx) * 128, bn0 = (idx % gx) * 128;
    const int wm = (w >> 1) * 64, wn = (w & 1) * 64;
    const int l15 = l & 15, lk = l >> 4;
    f32x4 acc[4][4] = {};
    const int nk = K >> 6;
    const unsigned short* Abase = A + (size_t)bm0 * K;
    const unsigned short* Wbase = W + (size_t)bn0 * K;
    for (int kt = 0; kt < nk; ++kt) {
        stage_rows<128>(Abase + kt * 64, K, lA, tid);
        stage_rows<128>(Wbase + kt * 64, K, lB, tid);
        __syncthreads();
        short8 af[4], bf[4];
#pragma unroll
        for (int kk = 0; kk < 2; ++kk) {
#pragma unroll
            for (int mf = 0; mf < 4; ++mf) {
                int r = wm + mf * 16 + l15;
                int c = (kk * 4 + lk) ^ (r & 7);
                af[mf] = *(const short8*)(lA + r * 64 + c * 8);
            }
#pragma unroll
            for (int nf = 0; nf < 4; ++nf) {
                int r = wn + nf * 16 + l15;
                int c = (kk * 4 + lk) ^ (r & 7);
                bf[nf] = *(const short8*)(lB + r * 64 + c * 8);
            }
#pragma unroll
            for (int mf = 0; mf < 4; ++mf)
#pragma unroll
                for (int nf = 0; nf < 4; ++nf)
                    acc[mf][nf] = __builtin_amdgcn_mfma_f32_16x16x32_bf16(af[mf], bf[nf], acc[mf][nf], 0, 0, 0);
        }
        __syncthreads();
    }
    const int row0 = bm0 + wm + (lk << 2);
    const int col0 = bn0 + wn + l15;
#pragma unroll
    for (int nf = 0; nf < 4; ++nf) {
        int col = col0 + nf * 16;
        float bv = bias[col];
#pragma unroll
        for (int mf = 0; mf < 4; ++mf) {
#pragma unroll
            for (int r = 0; r < 4; ++r) {
                int row = row0 + mf * 16 + r;
                float v = acc[mf][nf][r] + bv;
                size_t idx2 = (size_t)row * N + col;
                if constexpr (EPI == 0) {
                    ((unsigned short*)out)[idx2] = f2b(v);
                } else if constexpr (EPI == 1) {
                    v += aux[(row & 7) * N + col];
                    ((float*)out)[idx2] = v;
                } else if constexpr (EPI == 2) {
                    v = 0.5f * v * (1.0f + erff(v * 0.70710678118f));
                    ((unsigned short*)out)[idx2] = f2b(v);
                } else if constexpr (EPI == 3) {
                    v += aux[idx2];
                    ((unsigned short*)out)[idx2] = f2b(v);
                } else {
                    ((float*)out)[idx2] = v;
                }
            }
        }
    }
}

// ---------------- scores GEMM: S = rs_n * (kv_raw @ qkg^T) - u_n * t[hq] ----------------
__global__ __launch_bounds__(256) void gemm_scores(const unsigned short* __restrict__ A,
                                                   const unsigned short* __restrict__ Qk,
                                                   const float2* __restrict__ stats,
                                                   const float* __restrict__ tcol,
                                                   float* __restrict__ S) {
    __shared__ __align__(16) unsigned short lA[128 * 64];
    __shared__ __align__(16) unsigned short lB[64 * 64];
    const int tid = threadIdx.x;
    const int l = tid & 63, w = tid >> 6;
    int lid = blockIdx.x;
    int idx = (lid & 7) * (gridDim.x >> 3) + (lid >> 3);
    const int bm0 = idx * 128;
    const int wm = (w >> 1) * 64, wn = (w & 1) * 32;
    const int l15 = l & 15, lk = l >> 4;
    f32x4 acc[4][2] = {};
    const unsigned short* Abase = A + (size_t)bm0 * 768;
    for (int kt = 0; kt < 12; ++kt) {
        stage_rows<128>(Abase + kt * 64, 768, lA, tid);
        stage_rows<64>(Qk + kt * 64, 768, lB, tid);
        __syncthreads();
        short8 af[4], bf[2];
#pragma unroll
        for (int kk = 0; kk < 2; ++kk) {
#pragma unroll
            for (int mf = 0; mf < 4; ++mf) {
                int r = wm + mf * 16 + l15;
                int c = (kk * 4 + lk) ^ (r & 7);
                af[mf] = *(const short8*)(lA + r * 64 + c * 8);
            }
#pragma unroll
            for (int nf = 0; nf < 2; ++nf) {
                int r = wn + nf * 16 + l15;
                int c = (kk * 4 + lk) ^ (r & 7);
                bf[nf] = *(const short8*)(lB + r * 64 + c * 8);
            }
#pragma unroll
            for (int mf = 0; mf < 4; ++mf)
#pragma unroll
                for (int nf = 0; nf < 2; ++nf)
                    acc[mf][nf] = __builtin_amdgcn_mfma_f32_16x16x32_bf16(af[mf], bf[nf], acc[mf][nf], 0, 0, 0);
        }
        __syncthreads();
    }
    const int row0 = bm0 + wm + (lk << 2);
    const int col0 = wn + l15;
    const float tv0 = tcol[col0], tv1 = tcol[col0 + 16];
#pragma unroll
    for (int mf = 0; mf < 4; ++mf)
#pragma unroll
        for (int r = 0; r < 4; ++r) {
            int row = row0 + mf * 16 + r;
            float2 st = stats[row];
            S[(size_t)row * 64 + col0]      = st.x * acc[mf][0][r] - st.y * tv0;
            S[(size_t)row * 64 + col0 + 16] = st.x * acc[mf][1][r] - st.y * tv1;
        }
}

// ---------------- attn_mix: softmax(S[b]) with rs folded in, mix over RAW kv, LN epilogue ----
__global__ __launch_bounds__(256) void attn_mix(const unsigned short* __restrict__ kvr,
                                                const float* __restrict__ S,
                                                const float2* __restrict__ stats,
                                                const float* __restrict__ lg,
                                                const float* __restrict__ lb,
                                                unsigned short* __restrict__ cmix) {
    __shared__ __align__(16) unsigned short at[64 * 64];      // 8 KB  (holds at*rs_n)
    __shared__ __align__(16) unsigned short kvT[384 * 64];    // 48 KB; Sl unions into it
    __shared__ float dl[64];                                  // d[hq] = sum_n at*u_n
    float* Sl = (float*)kvT;
    const int b = blockIdx.x;
    const int t = threadIdx.x, l = t & 63, w = t >> 6;
    const int l15 = l & 15, lk = l >> 4;

    for (int i = t; i < 3136; i += 256) Sl[i] = S[(size_t)b * 3136 + i];
    __syncthreads();
    if (w == 0) {
        float mx = -1e30f;
        for (int n = 0; n < 49; ++n) mx = fmaxf(mx, Sl[n * 64 + l]);
        float sum = 0.f;
        for (int n = 0; n < 49; ++n) sum += __expf(Sl[n * 64 + l] - mx);
        float inv = 1.0f / sum;
        float dacc = 0.f;
#pragma unroll
        for (int c = 0; c < 8; ++c) {
            int cc = c ^ (l & 7);
            for (int j = 0; j < 8; ++j) {
                int n = c * 8 + j;
                float av = 0.f;
                if (n < 49) {
                    float a = __expf(Sl[n * 64 + l] - mx) * inv;
                    float2 st = stats[(size_t)b * 49 + n];
                    av = a * st.x;
                    dacc += a * st.y;
                }
                at[l * 64 + cc * 8 + j] = f2b(av);
            }
        }
        dl[l] = dacc;
    }
    __syncthreads();  // softmax done reading Sl; kvT may now overwrite it

    const unsigned short* src = kvr + ((size_t)b * 49 + (l < 49 ? l : 0)) * 768;
#pragma unroll 1
    for (int half = 0; half < 2; ++half) {
        for (int i = 0; i < 12; ++i) {
            int e0 = w * 8 + i * 32;
            ushort8 v = {0, 0, 0, 0, 0, 0, 0, 0};
            if (l < 49) v = *(const ushort8*)(src + half * 384 + e0);
#pragma unroll
            for (int j = 0; j < 8; ++j) {
                int e = e0 + j;
                kvT[e * 64 + (((l >> 3) ^ (e & 7)) << 3) + (l & 7)] = v[j];
            }
        }
        __syncthreads();
#pragma unroll 1
        for (int c2 = 0; c2 < 2; ++c2) {
            int ebase = w * 96 + c2 * 48;
            f32x4 acc[4][3] = {};
#pragma unroll
            for (int ks = 0; ks < 2; ++ks) {
                short8 af[4], bf[3];
#pragma unroll
                for (int mf = 0; mf < 4; ++mf) {
                    int r = mf * 16 + l15;
                    af[mf] = *(const short8*)(at + r * 64 + (((ks * 4 + lk) ^ (r & 7)) << 3));
                }
#pragma unroll
                for (int nf = 0; nf < 3; ++nf) {
                    int er = ebase + nf * 16 + l15;
                    bf[nf] = *(const short8*)(kvT + er * 64 + (((ks * 4 + lk) ^ (er & 7)) << 3));
                }
#pragma unroll
                for (int mf = 0; mf < 4; ++mf)
#pragma unroll
                    for (int nf = 0; nf < 3; ++nf)
                        acc[mf][nf] = __builtin_amdgcn_mfma_f32_16x16x32_bf16(af[mf], bf[nf], acc[mf][nf], 0, 0, 0);
            }
#pragma unroll
            for (int nf = 0; nf < 3; ++nf) {
                int e = half * 384 + ebase + nf * 16 + l15;
                float gg = lg[e], bbv = lb[e];
#pragma unroll
                for (int mf = 0; mf < 4; ++mf)
#pragma unroll
                    for (int r = 0; r < 4; ++r) {
                        int hq = mf * 16 + lk * 4 + r;
                        float val = gg * (acc[mf][nf][r] - dl[hq]) + bbv;
                        cmix[((size_t)(hq >> 3) * 16384 + b * 8 + (hq & 7)) * 768 + e] = f2b(val);
                    }
            }
        }
        __syncthreads();
    }
}

// ---------------- gemm_ctx: per-h ctx = cmix_h @ wv_h^T + bv_h (16384 x 96, K=768) ----------------
__global__ __launch_bounds__(256) void gemm_ctx(const unsigned short* __restrict__ cmix,
                                                const unsigned short* __restrict__ wvb,
                                                const float* __restrict__ bv,
                                                unsigned short* __restrict__ ctx) {
    __shared__ __align__(16) unsigned short lA[128 * 64];
    __shared__ __align__(16) unsigned short lB[128 * 64];
    const int tid = threadIdx.x;
    const int l = tid & 63, w = tid >> 6;
    const int h = blockIdx.z;
    int yy = blockIdx.y;
    int idx = (yy & 7) * 16 + (yy >> 3);
    const int bm0 = idx * 128;
    const int wm = (w >> 1) * 64, wn = (w & 1) * 64;
    const int l15 = l & 15, lk = l >> 4;
    f32x4 acc[4][4] = {};
    const unsigned short* Abase = cmix + (size_t)h * 16384 * 768 + (size_t)bm0 * 768;
    const unsigned short* Wbase = wvb + (size_t)h * 96 * 768;  // rows 96..127 over-read land in next ws region (finite)
    for (int kt = 0; kt < 12; ++kt) {
        stage_rows<128>(Abase + kt * 64, 768, lA, tid);
        stage_rows<128>(Wbase + kt * 64, 768, lB, tid);
        __syncthreads();
        short8 af[4], bf[4];
#pragma unroll
        for (int kk = 0; kk < 2; ++kk) {
#pragma unroll
            for (int mf = 0; mf < 4; ++mf) {
                int r = wm + mf * 16 + l15;
                int c = (kk * 4 + lk) ^ (r & 7);
                af[mf] = *(const short8*)(lA + r * 64 + c * 8);
            }
#pragma unroll
            for (int nf = 0; nf < 4; ++nf) {
                int r = wn + nf * 16 + l15;
                int c = (kk * 4 + lk) ^ (r & 7);
                bf[nf] = *(const short8*)(lB + r * 64 + c * 8);
            }
#pragma unroll
            for (int mf = 0; mf < 4; ++mf)
#pragma unroll
                for (int nf = 0; nf < 4; ++nf)
                    acc[mf][nf] = __builtin_amdgcn_mfma_f32_16x16x32_bf16(af[mf], bf[nf], acc[mf][nf], 0, 0, 0);
        }
        __syncthreads();
    }
    const int row0 = bm0 + wm + (lk << 2);
    const int col0 = wn + l15;
#pragma unroll
    for (int nf = 0; nf < 4; ++nf) {
        int col = col0 + nf * 16;
        if (col >= 96) continue;
        float bvv = bv[h * 96 + col];
#pragma unroll
        for (int mf = 0; mf < 4; ++mf)
#pragma unroll
            for (int r = 0; r < 4; ++r) {
                int row = row0 + mf * 16 + r;
                ctx[(size_t)row * 768 + h * 96 + col] = f2b(acc[mf][nf][r] + bvv);
            }
    }
}

// ---------------- host ----------------
extern "C" void kernel_launch(void* const* d_in, const int* in_sizes, int n_in,
                              void* d_out, int out_size, void* d_ws, size_t ws_size,
                              hipStream_t stream) {
    (void)in_sizes; (void)n_in; (void)out_size;
    const float* features      = (const float*)d_in[0];
    const float* input_proj_w  = (const float*)d_in[1];
    const float* input_proj_b  = (const float*)d_in[2];
    const float* queries       = (const float*)d_in[3];
    const float* ln_q_g        = (const float*)d_in[4];
    const float* ln_q_b        = (const float*)d_in[5];
    const float* ln_kv_g       = (const float*)d_in[6];
    const float* ln_kv_b       = (const float*)d_in[7];
    const float* in_proj_w     = (const float*)d_in[8];
    const float* in_proj_b     = (const float*)d_in[9];
    const float* out_proj_w    = (const float*)d_in[10];
    const float* out_proj_b    = (const float*)d_in[11];
    const float* ln_ff_g       = (const float*)d_in[12];
    const float* ln_ff_b       = (const float*)d_in[13];
    const float* ffn_w1        = (const float*)d_in[14];
    const float* ffn_b1        = (const float*)d_in[15];
    const float* ffn_w2        = (const float*)d_in[16];
    const float* ffn_b2        = (const float*)d_in[17];
    const float* output_proj_w = (const float*)d_in[18];
    const float* output_proj_b = (const float*)d_in[19];
    const float* final_g       = (const float*)d_in[20];
    const float* final_b       = (const float*)d_in[21];

    char* ws = (char*)d_ws;
    size_t off = 0;
    auto alloc = [&](size_t bytes) -> char* {
        char* r = ws + off; off += (bytes + 255) & ~(size_t)255; return r;
    };
    unsigned short* featb = (unsigned short*)alloc(100352ull * 320 * 2);    // 64 MB
    unsigned short* kvbuf = (unsigned short*)alloc(100352ull * 768 * 2);    // 154 MB (raw kv)
    unsigned short* cmix  = (unsigned short*)alloc(8ull * 16384 * 768 * 2); // 201 MB
    float*          S     = (float*)alloc(100352ull * 64 * 4);              // 26 MB
    float2*         stats = (float2*)alloc(100352ull * 8);                  // 0.8 MB
    unsigned short* winb  = (unsigned short*)alloc(768ull * 320 * 2);
    unsigned short* wvb   = (unsigned short*)alloc(768ull * 768 * 2);
    unsigned short* woutb = (unsigned short*)alloc(768ull * 768 * 2);
    unsigned short* w1b   = (unsigned short*)alloc(768ull * 768 * 2);
    unsigned short* w2b   = (unsigned short*)alloc(768ull * 768 * 2);
    unsigned short* wopb  = (unsigned short*)alloc(3072ull * 768 * 2);
    float* qnorm          = (float*)alloc(8 * 768 * 4);
    float* qpb            = (float*)alloc(8 * 768 * 4);
    unsigned short* qkb   = (unsigned short*)alloc(64ull * 768 * 2);
    float* tbuf           = (float*)alloc(64 * 4);
    if (off > ws_size) return;  // fail visibly (output stays poisoned)

    // region reuse (dead by the time they're overwritten):
    unsigned short* ctx  = featb;                                  // featb dead after kv GEMM
    unsigned short* outb = kvbuf;                                  // kvbuf dead after attn_mix; 100 MB <= 154 MB
    float* x             = (float*)cmix;                           // cmix dead after gemm_ctx
    unsigned short* hn   = (unsigned short*)((char*)cmix + 50331648);
    unsigned short* f1   = (unsigned short*)((char*)cmix + 75497472);
    unsigned short* x2   = (unsigned short*)((char*)cmix + 100663296);

    // weight/input casts to bf16
    cast_f2b<<<31360, 256, 0, stream>>>(features, featb, 8028160);
    cast_f2b<<<240,   256, 0, stream>>>(input_proj_w, winb, 61440);
    cast_f2b<<<576,   256, 0, stream>>>(in_proj_w + 2 * 768 * 768, wvb, 147456);  // wv
    cast_f2b<<<576,   256, 0, stream>>>(out_proj_w, woutb, 147456);
    cast_f2b<<<576,   256, 0, stream>>>(ffn_w1, w1b, 147456);
    cast_f2b<<<576,   256, 0, stream>>>(ffn_w2, w2b, 147456);
    cast_f2b<<<2304,  256, 0, stream>>>(output_proj_w, wopb, 589824);

    // batch-independent query path (fp32, tiny)
    ln_rows<768, false, false><<<2, 256, 0, stream>>>(queries, qnorm, ln_q_g, ln_q_b, 8);
    qp_kernel<<<24, 256, 0, stream>>>(qnorm, in_proj_w, in_proj_b, qpb);
    qk_build<<<64, 256, 0, stream>>>(qpb, in_proj_w + 768 * 768, ln_kv_g, qkb, tbuf);

    // kv = features @ Win^T + b  -> bf16 (raw, un-normalized)
    gemm_bf16<0><<<dim3(6, 784), 256, 0, stream>>>(featb, winb, input_proj_b, kvbuf, nullptr, 320, 768);
    // per-row LN stats (rs, rs*mu)
    ln_stats<<<25088, 256, 0, stream>>>(kvbuf, stats, 100352);
    // S = rs*(kv_raw @ qkg^T) - u*t  (LN folded into epilogue)
    gemm_scores<<<784, 256, 0, stream>>>(kvbuf, qkb, stats, tbuf, S);
    // cmix[h][bq][e] = g[e]*(softmax(S)*rs @ kv_raw - d[hq]) + beta[e]
    attn_mix<<<2048, 256, 0, stream>>>(kvbuf, S, stats, ln_kv_g, ln_kv_b, cmix);
    // ctx = cmix @ wv^T + bv (per h; sum(attn)=1 makes bias exact)
    gemm_ctx<<<dim3(1, 128, 8), 256, 0, stream>>>(cmix, wvb, in_proj_b + 1536, ctx);
    // x = ctx @ out_proj^T + b + queries  -> f32
    gemm_bf16<1><<<dim3(6, 128), 256, 0, stream>>>(ctx, woutb, out_proj_b, x, queries, 768, 768);
    // h = LN(x) -> bf16
    ln_rows<768, false, true><<<4096, 256, 0, stream>>>(x, hn, ln_ff_g, ln_ff_b, 16384);
    // f1 = gelu(h @ w1^T + b1) -> bf16
    gemm_bf16<2><<<dim3(6, 128), 256, 0, stream>>>(hn, w1b, ffn_b1, f1, nullptr, 768, 768);
    // x2 = f1 @ w2^T + b2 + x -> bf16
    gemm_bf16<3><<<dim3(6, 128), 256, 0, stream>>>(f1, w2b, ffn_b2, x2, x, 768, 768);
    // out_pre = x2 @ Wop^T + b -> bf16 (workspace), halves the f32 write
    gemm_bf16<0><<<dim3(24, 128), 256, 0, stream>>>(x2, wopb, output_proj_b, outb, nullptr, 768, 3072);
    // final LN: bf16 in -> f32 d_out
    ln_rows<3072, true, false><<<4096, 256, 0, stream>>>(outb, (float*)d_out, final_g, final_b, 16384);
}